// Round 6
// baseline (73.106 us; speedup 1.0000x reference)
//
#include <hip/hip_runtime.h>

#define N_ROIS 32768
#define N_GT   1024
#define N_IMG  8
#define CHUNKS 16                         // lanes cooperating per ROI (main kernel)
#define MBLOCK 512                        // main kernel block size (8 waves)
#define MGRID  256                        // 1 block per CU
#define ROIS_PER_PASS (MBLOCK / CHUNKS)   // 32
#define ROIS_PER_BLOCK (N_ROIS / MGRID)   // 128
#define PASSES (ROIS_PER_BLOCK / ROIS_PER_PASS) // 4

// d_ws layout (floats):
//   [0    .. 4095]  sorted gt box float4 (x1,y1,x2,y2)
//   [4096 .. 5119]  sorted gt area
//   [5120 .. 6143]  sorted gt original index (int bits)
//   [6144 .. 6152]  segment bounds seg[0..8] (int bits)
#define WS_BOX  0
#define WS_AREA 4096
#define WS_OJ   5120
#define WS_SEG  6144

// ---------------------------------------------------------------------------
// Pre-kernel: stable counting sort of GT boxes by batch index. 1 block x 256
// (4 waves). All global loads prefetched into registers up front (one batched
// round-trip); wave w owns chunks 4w..4w+3. Sorted order is stable (original-
// index order within each batch) — required for numpy argmax tie-breaks.
// ---------------------------------------------------------------------------
__global__ __launch_bounds__(256) void gt_sort_kernel(
    const float* __restrict__ gt_boxes,   // (N_GT, 5)
    const int*   __restrict__ gt_b,       // (N_GT,)
    float*       __restrict__ ws)
{
    __shared__ int s_chist[16][N_IMG];    // counts per (chunk, batch)
    __shared__ int s_cbase[16][N_IMG];    // global base per (chunk, batch)

    int tid  = threadIdx.x;
    int lane = tid & 63;
    int wave = tid >> 6;                  // 0..3; owns chunks 4w..4w+3

    unsigned long long lt_mask = (lane == 63) ? (~0ull >> 1)
                                              : ((1ull << lane) - 1ull);

    // ---- Phase 0: prefetch everything (20 independent loads, one round-trip)
    int   bv[4];
    float bx1[4], by1[4], bx2[4], by2[4];
    #pragma unroll
    for (int k = 0; k < 4; ++k) {
        int j = (wave * 4 + k) * 64 + lane;
        bv[k]  = gt_b[j];
        bx1[k] = gt_boxes[j * 5 + 0];
        by1[k] = gt_boxes[j * 5 + 1];
        bx2[k] = gt_boxes[j * 5 + 2];
        by2[k] = gt_boxes[j * 5 + 3];
    }

    // ---- Phase 1: per-chunk histograms + stable in-chunk ranks via ballots
    int rankc[4];
    #pragma unroll
    for (int k = 0; k < 4; ++k) {
        int b = bv[k];
        unsigned long long mym = 0;
        #pragma unroll
        for (int bb = 0; bb < N_IMG; ++bb) {
            unsigned long long m = __ballot(b == bb);
            if (b == bb) mym = m;
            if (lane == bb) s_chist[wave * 4 + k][bb] = __popcll(m);
        }
        rankc[k] = __popcll(mym & lt_mask);
    }
    __syncthreads();

    // ---- Phase 2: wave 0 computes chunk bases via in-register shfl scan
    if (wave == 0) {
        int myc    = lane & 15;           // chunk
        int myb_lo = lane >> 4;           // batch (2 slots per lane)
        int myb_hi = myb_lo + 4;
        int cnt_lo = s_chist[myc][myb_lo];
        int cnt_hi = s_chist[myc][myb_hi];
        int inc_lo = cnt_lo, inc_hi = cnt_hi;
        #pragma unroll
        for (int d = 1; d < 16; d <<= 1) {
            int t_lo = __shfl_up(inc_lo, d, 16);
            int t_hi = __shfl_up(inc_hi, d, 16);
            if (myc >= d) { inc_lo += t_lo; inc_hi += t_hi; }
        }
        int t0 = __shfl(inc_lo, 15, 64);
        int t1 = __shfl(inc_lo, 31, 64);
        int t2 = __shfl(inc_lo, 47, 64);
        int t3 = __shfl(inc_lo, 63, 64);
        int t4 = __shfl(inc_hi, 15, 64);
        int t5 = __shfl(inc_hi, 31, 64);
        int t6 = __shfl(inc_hi, 47, 64);
        int t7 = __shfl(inc_hi, 63, 64);

        int s0 = 0;
        int s1 = s0 + t0, s2 = s1 + t1, s3 = s2 + t2, s4 = s3 + t3;
        int s5 = s4 + t4, s6 = s5 + t5, s7 = s6 + t6, s8 = s7 + t7; // == N_GT

        if (lane == 0) {                  // unrolled scalar stores, no scratch
            int* wseg = (int*)(ws + WS_SEG);
            wseg[0] = s0; wseg[1] = s1; wseg[2] = s2; wseg[3] = s3;
            wseg[4] = s4; wseg[5] = s5; wseg[6] = s6; wseg[7] = s7;
            wseg[8] = s8;
        }
        int seg_lo = (myb_lo == 0) ? s0 : (myb_lo == 1) ? s1
                   : (myb_lo == 2) ? s2 : s3;
        int seg_hi = (myb_hi == 4) ? s4 : (myb_hi == 5) ? s5
                   : (myb_hi == 6) ? s6 : s7;
        s_cbase[myc][myb_lo] = seg_lo + (inc_lo - cnt_lo);
        s_cbase[myc][myb_hi] = seg_hi + (inc_hi - cnt_hi);
    }
    __syncthreads();

    // ---- Phase 3: stable scatter from prefetched registers (no new loads)
    float4* wbox  = (float4*)(ws + WS_BOX);
    float*  warea = ws + WS_AREA;
    int*    woj   = (int*)(ws + WS_OJ);
    #pragma unroll
    for (int k = 0; k < 4; ++k) {
        int chunk = wave * 4 + k;
        int j     = chunk * 64 + lane;
        int rank  = s_cbase[chunk][bv[k]] + rankc[k];
        wbox[rank]  = make_float4(bx1[k], by1[k], bx2[k], by2[k]);
        // numpy f32 op order: ((x2-x1)+1) * ((y2-y1)+1)
        warea[rank] = __fmul_rn(__fadd_rn(__fsub_rn(bx2[k], bx1[k]), 1.0f),
                                __fadd_rn(__fsub_rn(by2[k], by1[k]), 1.0f));
        woj[rank]   = j;
    }
}

// ---------------------------------------------------------------------------
// Main kernel: 256 blocks (1/CU) x 512 threads. Each block stages the sorted
// 24.5 KB GT table ONCE, then grid-strides over 128 ROIs (4 passes x 32 ROIs
// x 16 lanes). v4: was 2048 blocks each re-staging the table = 50 MB of
// L3/HBM re-reads; now 256 stagings = 6 MB.
// ---------------------------------------------------------------------------
__global__ __launch_bounds__(MBLOCK) void roi_target_kernel(
    const float* __restrict__ rois,       // (N_ROIS, 5)
    const int*   __restrict__ roi_b,      // (N_ROIS,)
    const float* __restrict__ gt_boxes,   // (N_GT, 5) -- labels in epilogue
    const float* __restrict__ ws,
    float*       __restrict__ out)        // labels ++ deltas ++ bbwgts
{
    __shared__ float4 s_box[N_GT];        // 16 KB sorted
    __shared__ float  s_area[N_GT];       //  4 KB
    __shared__ int    s_oj[N_GT];         //  4 KB original index
    __shared__ int    s_seg[N_IMG + 1];

    const float4* wbox  = (const float4*)(ws + WS_BOX);
    const float*  warea = ws + WS_AREA;
    const int*    woj   = (const int*)(ws + WS_OJ);
    const int*    wseg  = (const int*)(ws + WS_SEG);

    for (int t = threadIdx.x; t < N_GT; t += MBLOCK) {
        s_box[t]  = wbox[t];
        s_area[t] = warea[t];
        s_oj[t]   = woj[t];
    }
    if (threadIdx.x <= N_IMG) s_seg[threadIdx.x] = wseg[threadIdx.x];
    __syncthreads();

    int c = threadIdx.x & (CHUNKS - 1);

    #pragma unroll
    for (int pass = 0; pass < PASSES; ++pass) {
        int roi = blockIdx.x * ROIS_PER_BLOCK + pass * ROIS_PER_PASS
                + (threadIdx.x >> 4);

        float rx1 = rois[roi * 5 + 0];
        float ry1 = rois[roi * 5 + 1];
        float rx2 = rois[roi * 5 + 2];
        float ry2 = rois[roi * 5 + 3];
        int   rb  = roi_b[roi];
        float area_r = __fmul_rn(__fadd_rn(__fsub_rn(rx2, rx1), 1.0f),
                                 __fadd_rn(__fsub_rn(ry2, ry1), 1.0f));

        int st = s_seg[rb];
        int en = s_seg[rb + 1];

        // Scan this batch's segment; positions increasing per lane, so strict >
        // keeps the first max. Within a batch, position order == original-j order.
        float best = -2.0f;
        int   bp   = -1;
        for (int p = st + c; p < en; p += CHUNKS) {
            float4 b  = s_box[p];
            float ix1 = fmaxf(rx1, b.x);
            float iy1 = fmaxf(ry1, b.y);
            float ix2 = fminf(rx2, b.z);
            float iy2 = fminf(ry2, b.w);
            float iw  = fmaxf(__fadd_rn(__fsub_rn(ix2, ix1), 1.0f), 0.0f);
            float ih  = fmaxf(__fadd_rn(__fsub_rn(iy2, iy1), 1.0f), 0.0f);
            float inter = __fmul_rn(iw, ih);
            // union = (area_r + area_g) - inter; contraction blocked (matches numpy)
            float uni = __fsub_rn(__fadd_rn(area_r, s_area[p]), inter);
            float v   = __fdiv_rn(inter, uni);
            if (v > best) { best = v; bp = p; }
        }

        // Cross-lane reduce over the 16-lane group; equal value -> smaller
        // position wins (== smaller original j within the batch).
        #pragma unroll
        for (int m = 1; m < CHUNKS; m <<= 1) {
            float vo = __shfl_xor(best, m, 64);
            int   po = __shfl_xor(bp,   m, 64);
            if (vo > best || (vo == best && po < bp)) { best = vo; bp = po; }
        }

        if (c == 0) {
            bool fg = (best >= 0.5f);      // best is bit-exact numpy max (or -2 -> false)
            int  pp = (bp < 0) ? 0 : bp;   // safe index; outputs zeroed when !fg

            float label = 0.0f;
            if (fg) label = gt_boxes[s_oj[pp] * 5 + 4];   // integral 1..80

            float4 g  = s_box[pp];
            float ew  = __fadd_rn(__fsub_rn(rx2, rx1), 1.0f);
            float eh  = __fadd_rn(__fsub_rn(ry2, ry1), 1.0f);
            float ecx = __fadd_rn(rx1, __fmul_rn(0.5f, ew));
            float ecy = __fadd_rn(ry1, __fmul_rn(0.5f, eh));
            float gw  = __fadd_rn(__fsub_rn(g.z, g.x), 1.0f);
            float gh  = __fadd_rn(__fsub_rn(g.w, g.y), 1.0f);
            float gcx = __fadd_rn(g.x, __fmul_rn(0.5f, gw));
            float gcy = __fadd_rn(g.y, __fmul_rn(0.5f, gh));

            float dx = __fdiv_rn(__fsub_rn(gcx, ecx), ew);
            float dy = __fdiv_rn(__fsub_rn(gcy, ecy), eh);
            float dw = logf(__fdiv_rn(gw, ew));
            float dh = logf(__fdiv_rn(gh, eh));

            if (!fg) { dx = 0.0f; dy = 0.0f; dw = 0.0f; dh = 0.0f; }
            float wgt = fg ? 1.0f : 0.0f;

            out[roi] = label;
            float4* dout = (float4*)(out + N_ROIS) + roi;
            *dout = make_float4(dx, dy, dw, dh);
            float4* wout = (float4*)(out + N_ROIS + 4 * N_ROIS) + roi;
            *wout = make_float4(wgt, wgt, wgt, wgt);
        }
    }
}

extern "C" void kernel_launch(void* const* d_in, const int* in_sizes, int n_in,
                              void* d_out, int out_size, void* d_ws, size_t ws_size,
                              hipStream_t stream) {
    const float* rois  = (const float*)d_in[0];   // (32768,5)
    const int*   roi_b = (const int*)d_in[1];     // (32768,)
    const float* gt    = (const float*)d_in[2];   // (1024,5)
    const int*   gt_b  = (const int*)d_in[3];     // (1024,)
    float*       ws    = (float*)d_ws;
    float*       out   = (float*)d_out;           // 32768*9 floats

    gt_sort_kernel<<<1, 256, 0, stream>>>(gt, gt_b, ws);
    roi_target_kernel<<<MGRID, MBLOCK, 0, stream>>>(rois, roi_b, gt, ws, out);
}

// Round 7
// 70.126 us; speedup vs baseline: 1.0425x; 1.0425x over previous
//
#include <hip/hip_runtime.h>

#define N_ROIS 32768
#define N_GT   1024
#define N_IMG  8
#define CHUNKS 16                         // lanes cooperating per ROI
#define MBLOCK 512                        // 8 waves
#define MGRID  256                        // 1 block per CU
#define ROIS_PER_PASS (MBLOCK / CHUNKS)   // 32
#define ROIS_PER_BLOCK (N_ROIS / MGRID)   // 128
#define PASSES (ROIS_PER_BLOCK / ROIS_PER_PASS) // 4
#define GT_CHUNKS 16                      // 1024 / 64
#define CHUNKS_PER_WAVE 2                 // 16 chunks / 8 waves

// ---------------------------------------------------------------------------
// Single fused kernel (v5). R6 evidence: per-dispatch overhead (~15 KB fill
// taking 40 µs in-graph) dwarfs our ~5 µs of compute, and the sort->main
// dependency serialized two dispatches. So every block now computes the
// stable batch-sort of the 1024 GT boxes redundantly in its own LDS (~1 µs:
// one batched 20 KB read + wave ballots) and then processes its 128 ROIs.
// One dispatch, no workspace, no inter-block dependencies.
//
// Sort logic (ballot histograms -> wave-0 shfl scan -> stable scatter) is
// bit-identical to v3/v4: within each batch, sorted position order ==
// original-index order, which reproduces numpy argmax first-index tie-break.
// ---------------------------------------------------------------------------
__global__ __launch_bounds__(MBLOCK) void roi_target_kernel(
    const float* __restrict__ rois,       // (N_ROIS, 5)
    const int*   __restrict__ roi_b,      // (N_ROIS,)
    const float* __restrict__ gt_boxes,   // (N_GT, 5)
    const int*   __restrict__ gt_b,       // (N_GT,)
    float*       __restrict__ out)        // labels ++ deltas ++ bbwgts
{
    __shared__ float4 s_box[N_GT];        // 16 KB sorted (x1,y1,x2,y2)
    __shared__ float  s_area[N_GT];       //  4 KB sorted area
    __shared__ float  s_lab[N_GT];        //  4 KB sorted label
    __shared__ int    s_chist[GT_CHUNKS][N_IMG];
    __shared__ int    s_cbase[GT_CHUNKS][N_IMG];
    __shared__ int    s_seg[N_IMG + 1];

    int tid  = threadIdx.x;
    int lane = tid & 63;
    int wave = tid >> 6;                  // 0..7; owns chunks 2w, 2w+1

    unsigned long long lt_mask = (lane == 63) ? (~0ull >> 1)
                                              : ((1ull << lane) - 1ull);

    // ---- Sort phase 0: prefetch this wave's 2 chunks (10 independent loads)
    int   bv[CHUNKS_PER_WAVE];
    float bx1[CHUNKS_PER_WAVE], by1[CHUNKS_PER_WAVE];
    float bx2[CHUNKS_PER_WAVE], by2[CHUNKS_PER_WAVE], blab[CHUNKS_PER_WAVE];
    #pragma unroll
    for (int k = 0; k < CHUNKS_PER_WAVE; ++k) {
        int j = (wave * CHUNKS_PER_WAVE + k) * 64 + lane;
        bv[k]   = gt_b[j];
        bx1[k]  = gt_boxes[j * 5 + 0];
        by1[k]  = gt_boxes[j * 5 + 1];
        bx2[k]  = gt_boxes[j * 5 + 2];
        by2[k]  = gt_boxes[j * 5 + 3];
        blab[k] = gt_boxes[j * 5 + 4];
    }

    // ---- Sort phase 1: per-chunk histograms + stable in-chunk ranks
    int rankc[CHUNKS_PER_WAVE];
    #pragma unroll
    for (int k = 0; k < CHUNKS_PER_WAVE; ++k) {
        int b = bv[k];
        unsigned long long mym = 0;
        #pragma unroll
        for (int bb = 0; bb < N_IMG; ++bb) {
            unsigned long long m = __ballot(b == bb);
            if (b == bb) mym = m;
            if (lane == bb) s_chist[wave * CHUNKS_PER_WAVE + k][bb] = __popcll(m);
        }
        rankc[k] = __popcll(mym & lt_mask);
    }
    __syncthreads();

    // ---- Sort phase 2: wave 0 computes chunk bases via in-register shfl scan
    if (wave == 0) {
        int myc    = lane & 15;           // chunk
        int myb_lo = lane >> 4;           // batches (2 slots per lane)
        int myb_hi = myb_lo + 4;
        int cnt_lo = s_chist[myc][myb_lo];
        int cnt_hi = s_chist[myc][myb_hi];
        int inc_lo = cnt_lo, inc_hi = cnt_hi;
        #pragma unroll
        for (int d = 1; d < 16; d <<= 1) {
            int t_lo = __shfl_up(inc_lo, d, 16);
            int t_hi = __shfl_up(inc_hi, d, 16);
            if (myc >= d) { inc_lo += t_lo; inc_hi += t_hi; }
        }
        int t0 = __shfl(inc_lo, 15, 64);
        int t1 = __shfl(inc_lo, 31, 64);
        int t2 = __shfl(inc_lo, 47, 64);
        int t3 = __shfl(inc_lo, 63, 64);
        int t4 = __shfl(inc_hi, 15, 64);
        int t5 = __shfl(inc_hi, 31, 64);
        int t6 = __shfl(inc_hi, 47, 64);
        int t7 = __shfl(inc_hi, 63, 64);

        int s0 = 0;
        int s1 = s0 + t0, s2 = s1 + t1, s3 = s2 + t2, s4 = s3 + t3;
        int s5 = s4 + t4, s6 = s5 + t5, s7 = s6 + t6, s8 = s7 + t7; // == N_GT

        if (lane == 0) {
            s_seg[0] = s0; s_seg[1] = s1; s_seg[2] = s2; s_seg[3] = s3;
            s_seg[4] = s4; s_seg[5] = s5; s_seg[6] = s6; s_seg[7] = s7;
            s_seg[8] = s8;
        }
        int seg_lo = (myb_lo == 0) ? s0 : (myb_lo == 1) ? s1
                   : (myb_lo == 2) ? s2 : s3;
        int seg_hi = (myb_hi == 4) ? s4 : (myb_hi == 5) ? s5
                   : (myb_hi == 6) ? s6 : s7;
        s_cbase[myc][myb_lo] = seg_lo + (inc_lo - cnt_lo);
        s_cbase[myc][myb_hi] = seg_hi + (inc_hi - cnt_hi);
    }
    __syncthreads();

    // ---- Sort phase 3: stable scatter into LDS from prefetched registers
    #pragma unroll
    for (int k = 0; k < CHUNKS_PER_WAVE; ++k) {
        int chunk = wave * CHUNKS_PER_WAVE + k;
        int rank  = s_cbase[chunk][bv[k]] + rankc[k];
        s_box[rank]  = make_float4(bx1[k], by1[k], bx2[k], by2[k]);
        // numpy f32 op order: ((x2-x1)+1) * ((y2-y1)+1)
        s_area[rank] = __fmul_rn(__fadd_rn(__fsub_rn(bx2[k], bx1[k]), 1.0f),
                                 __fadd_rn(__fsub_rn(by2[k], by1[k]), 1.0f));
        s_lab[rank]  = blab[k];
    }
    __syncthreads();

    // ---- ROI phase: 16 lanes per ROI scan the ROI's batch segment (~128 GT)
    int c = tid & (CHUNKS - 1);

    #pragma unroll
    for (int pass = 0; pass < PASSES; ++pass) {
        int roi = blockIdx.x * ROIS_PER_BLOCK + pass * ROIS_PER_PASS
                + (tid >> 4);

        float rx1 = rois[roi * 5 + 0];
        float ry1 = rois[roi * 5 + 1];
        float rx2 = rois[roi * 5 + 2];
        float ry2 = rois[roi * 5 + 3];
        int   rb  = roi_b[roi];
        float area_r = __fmul_rn(__fadd_rn(__fsub_rn(rx2, rx1), 1.0f),
                                 __fadd_rn(__fsub_rn(ry2, ry1), 1.0f));

        int st = s_seg[rb];
        int en = s_seg[rb + 1];

        // Positions increasing per lane, so strict > keeps the first max.
        // Within a batch, position order == original-j order.
        float best = -2.0f;
        int   bp   = -1;
        for (int p = st + c; p < en; p += CHUNKS) {
            float4 b  = s_box[p];
            float ix1 = fmaxf(rx1, b.x);
            float iy1 = fmaxf(ry1, b.y);
            float ix2 = fminf(rx2, b.z);
            float iy2 = fminf(ry2, b.w);
            float iw  = fmaxf(__fadd_rn(__fsub_rn(ix2, ix1), 1.0f), 0.0f);
            float ih  = fmaxf(__fadd_rn(__fsub_rn(iy2, iy1), 1.0f), 0.0f);
            float inter = __fmul_rn(iw, ih);
            // union = (area_r + area_g) - inter; contraction blocked (numpy)
            float uni = __fsub_rn(__fadd_rn(area_r, s_area[p]), inter);
            float v   = __fdiv_rn(inter, uni);
            if (v > best) { best = v; bp = p; }
        }

        // Cross-lane reduce over the 16-lane group; equal value -> smaller
        // position wins (== smaller original j within the batch).
        #pragma unroll
        for (int m = 1; m < CHUNKS; m <<= 1) {
            float vo = __shfl_xor(best, m, 64);
            int   po = __shfl_xor(bp,   m, 64);
            if (vo > best || (vo == best && po < bp)) { best = vo; bp = po; }
        }

        if (c == 0) {
            bool fg = (best >= 0.5f);      // bit-exact numpy max (or -2 -> false)
            int  pp = (bp < 0) ? 0 : bp;   // safe index; outputs zeroed if !fg

            float label = fg ? s_lab[pp] : 0.0f;   // integral 1..80, exact

            float4 g  = s_box[pp];
            float ew  = __fadd_rn(__fsub_rn(rx2, rx1), 1.0f);
            float eh  = __fadd_rn(__fsub_rn(ry2, ry1), 1.0f);
            float ecx = __fadd_rn(rx1, __fmul_rn(0.5f, ew));
            float ecy = __fadd_rn(ry1, __fmul_rn(0.5f, eh));
            float gw  = __fadd_rn(__fsub_rn(g.z, g.x), 1.0f);
            float gh  = __fadd_rn(__fsub_rn(g.w, g.y), 1.0f);
            float gcx = __fadd_rn(g.x, __fmul_rn(0.5f, gw));
            float gcy = __fadd_rn(g.y, __fmul_rn(0.5f, gh));

            float dx = __fdiv_rn(__fsub_rn(gcx, ecx), ew);
            float dy = __fdiv_rn(__fsub_rn(gcy, ecy), eh);
            float dw = logf(__fdiv_rn(gw, ew));
            float dh = logf(__fdiv_rn(gh, eh));

            if (!fg) { dx = 0.0f; dy = 0.0f; dw = 0.0f; dh = 0.0f; }
            float wgt = fg ? 1.0f : 0.0f;

            out[roi] = label;
            float4* dout = (float4*)(out + N_ROIS) + roi;
            *dout = make_float4(dx, dy, dw, dh);
            float4* wout = (float4*)(out + N_ROIS + 4 * N_ROIS) + roi;
            *wout = make_float4(wgt, wgt, wgt, wgt);
        }
    }
}

extern "C" void kernel_launch(void* const* d_in, const int* in_sizes, int n_in,
                              void* d_out, int out_size, void* d_ws, size_t ws_size,
                              hipStream_t stream) {
    const float* rois  = (const float*)d_in[0];   // (32768,5)
    const int*   roi_b = (const int*)d_in[1];     // (32768,)
    const float* gt    = (const float*)d_in[2];   // (1024,5)
    const int*   gt_b  = (const int*)d_in[3];     // (1024,)
    float*       out   = (float*)d_out;           // 32768*9 floats

    roi_target_kernel<<<MGRID, MBLOCK, 0, stream>>>(rois, roi_b, gt, gt_b, out);
}

// Round 8
// 67.368 us; speedup vs baseline: 1.0852x; 1.0409x over previous
//
#include <hip/hip_runtime.h>

#define N_ROIS 32768
#define N_GT   1024
#define N_IMG  8
#define CHUNKS 16                         // lanes cooperating per ROI
#define MBLOCK 512                        // 8 waves
#define MGRID  512                        // 2 blocks per CU resident
#define ROIS_PER_PASS (MBLOCK / CHUNKS)   // 32
#define ROIS_PER_BLOCK (N_ROIS / MGRID)   // 64
#define PASSES (ROIS_PER_BLOCK / ROIS_PER_PASS) // 2
#define GT_CHUNKS 16                      // 1024 / 64
#define CHUNKS_PER_WAVE 2                 // 16 chunks / 8 waves

// ---------------------------------------------------------------------------
// Single fused kernel (v6). R7 evidence: fused kernel ≈24 µs timed vs ~4 µs
// issue-rate model — latency-bound at 1 block/CU (2 waves/SIMD) with a serial
// ds_read(~120cyc)->minmax->div(~30cyc) chain per iteration. v6: grid 512
// (2 blocks/CU = 4 waves/SIMD), ROI data prefetched under the sort phase,
// inner scan unrolled 2x for independent in-flight chains.
//
// Sort logic (ballot histograms -> wave-0 shfl scan -> stable scatter) is
// bit-identical to v3..v5: within each batch, sorted position order ==
// original-index order, reproducing numpy argmax first-index tie-break.
// ---------------------------------------------------------------------------
__global__ __launch_bounds__(MBLOCK) void roi_target_kernel(
    const float* __restrict__ rois,       // (N_ROIS, 5)
    const int*   __restrict__ roi_b,      // (N_ROIS,)
    const float* __restrict__ gt_boxes,   // (N_GT, 5)
    const int*   __restrict__ gt_b,       // (N_GT,)
    float*       __restrict__ out)        // labels ++ deltas ++ bbwgts
{
    __shared__ float4 s_box[N_GT];        // 16 KB sorted (x1,y1,x2,y2)
    __shared__ float  s_area[N_GT];       //  4 KB sorted area
    __shared__ float  s_lab[N_GT];        //  4 KB sorted label
    __shared__ int    s_chist[GT_CHUNKS][N_IMG];
    __shared__ int    s_cbase[GT_CHUNKS][N_IMG];
    __shared__ int    s_seg[N_IMG + 1];

    int tid  = threadIdx.x;
    int lane = tid & 63;
    int wave = tid >> 6;                  // 0..7; owns chunks 2w, 2w+1

    unsigned long long lt_mask = (lane == 63) ? (~0ull >> 1)
                                              : ((1ull << lane) - 1ull);

    // ---- Phase 0: prefetch GT chunks AND this thread's ROI data (pass 0 +
    // pass 1) in one batched round-trip; latency hides under the ballots.
    int   bv[CHUNKS_PER_WAVE];
    float bx1[CHUNKS_PER_WAVE], by1[CHUNKS_PER_WAVE];
    float bx2[CHUNKS_PER_WAVE], by2[CHUNKS_PER_WAVE], blab[CHUNKS_PER_WAVE];
    #pragma unroll
    for (int k = 0; k < CHUNKS_PER_WAVE; ++k) {
        int j = (wave * CHUNKS_PER_WAVE + k) * 64 + lane;
        bv[k]   = gt_b[j];
        bx1[k]  = gt_boxes[j * 5 + 0];
        by1[k]  = gt_boxes[j * 5 + 1];
        bx2[k]  = gt_boxes[j * 5 + 2];
        by2[k]  = gt_boxes[j * 5 + 3];
        blab[k] = gt_boxes[j * 5 + 4];
    }
    float prx1[PASSES], pry1[PASSES], prx2[PASSES], pry2[PASSES];
    int   prb[PASSES];
    #pragma unroll
    for (int ps = 0; ps < PASSES; ++ps) {
        int roi = blockIdx.x * ROIS_PER_BLOCK + ps * ROIS_PER_PASS + (tid >> 4);
        prx1[ps] = rois[roi * 5 + 0];
        pry1[ps] = rois[roi * 5 + 1];
        prx2[ps] = rois[roi * 5 + 2];
        pry2[ps] = rois[roi * 5 + 3];
        prb[ps]  = roi_b[roi];
    }

    // ---- Sort phase 1: per-chunk histograms + stable in-chunk ranks
    int rankc[CHUNKS_PER_WAVE];
    #pragma unroll
    for (int k = 0; k < CHUNKS_PER_WAVE; ++k) {
        int b = bv[k];
        unsigned long long mym = 0;
        #pragma unroll
        for (int bb = 0; bb < N_IMG; ++bb) {
            unsigned long long m = __ballot(b == bb);
            if (b == bb) mym = m;
            if (lane == bb) s_chist[wave * CHUNKS_PER_WAVE + k][bb] = __popcll(m);
        }
        rankc[k] = __popcll(mym & lt_mask);
    }
    __syncthreads();

    // ---- Sort phase 2: wave 0 computes chunk bases via in-register shfl scan
    if (wave == 0) {
        int myc    = lane & 15;           // chunk
        int myb_lo = lane >> 4;           // batches (2 slots per lane)
        int myb_hi = myb_lo + 4;
        int cnt_lo = s_chist[myc][myb_lo];
        int cnt_hi = s_chist[myc][myb_hi];
        int inc_lo = cnt_lo, inc_hi = cnt_hi;
        #pragma unroll
        for (int d = 1; d < 16; d <<= 1) {
            int t_lo = __shfl_up(inc_lo, d, 16);
            int t_hi = __shfl_up(inc_hi, d, 16);
            if (myc >= d) { inc_lo += t_lo; inc_hi += t_hi; }
        }
        int t0 = __shfl(inc_lo, 15, 64);
        int t1 = __shfl(inc_lo, 31, 64);
        int t2 = __shfl(inc_lo, 47, 64);
        int t3 = __shfl(inc_lo, 63, 64);
        int t4 = __shfl(inc_hi, 15, 64);
        int t5 = __shfl(inc_hi, 31, 64);
        int t6 = __shfl(inc_hi, 47, 64);
        int t7 = __shfl(inc_hi, 63, 64);

        int s0 = 0;
        int s1 = s0 + t0, s2 = s1 + t1, s3 = s2 + t2, s4 = s3 + t3;
        int s5 = s4 + t4, s6 = s5 + t5, s7 = s6 + t6, s8 = s7 + t7; // == N_GT

        if (lane == 0) {
            s_seg[0] = s0; s_seg[1] = s1; s_seg[2] = s2; s_seg[3] = s3;
            s_seg[4] = s4; s_seg[5] = s5; s_seg[6] = s6; s_seg[7] = s7;
            s_seg[8] = s8;
        }
        int seg_lo = (myb_lo == 0) ? s0 : (myb_lo == 1) ? s1
                   : (myb_lo == 2) ? s2 : s3;
        int seg_hi = (myb_hi == 4) ? s4 : (myb_hi == 5) ? s5
                   : (myb_hi == 6) ? s6 : s7;
        s_cbase[myc][myb_lo] = seg_lo + (inc_lo - cnt_lo);
        s_cbase[myc][myb_hi] = seg_hi + (inc_hi - cnt_hi);
    }
    __syncthreads();

    // ---- Sort phase 3: stable scatter into LDS from prefetched registers
    #pragma unroll
    for (int k = 0; k < CHUNKS_PER_WAVE; ++k) {
        int chunk = wave * CHUNKS_PER_WAVE + k;
        int rank  = s_cbase[chunk][bv[k]] + rankc[k];
        s_box[rank]  = make_float4(bx1[k], by1[k], bx2[k], by2[k]);
        // numpy f32 op order: ((x2-x1)+1) * ((y2-y1)+1)
        s_area[rank] = __fmul_rn(__fadd_rn(__fsub_rn(bx2[k], bx1[k]), 1.0f),
                                 __fadd_rn(__fsub_rn(by2[k], by1[k]), 1.0f));
        s_lab[rank]  = blab[k];
    }
    __syncthreads();

    // ---- ROI phase: 16 lanes per ROI scan the ROI's batch segment (~128 GT)
    int c = tid & (CHUNKS - 1);

    #pragma unroll
    for (int pass = 0; pass < PASSES; ++pass) {
        int roi = blockIdx.x * ROIS_PER_BLOCK + pass * ROIS_PER_PASS
                + (tid >> 4);

        float rx1 = prx1[pass], ry1 = pry1[pass];
        float rx2 = prx2[pass], ry2 = pry2[pass];
        int   rb  = prb[pass];
        float area_r = __fmul_rn(__fadd_rn(__fsub_rn(rx2, rx1), 1.0f),
                                 __fadd_rn(__fsub_rn(ry2, ry1), 1.0f));

        int st = s_seg[rb];
        int en = s_seg[rb + 1];

        // Positions increasing per lane, so strict > keeps the first max.
        // Within a batch, position order == original-j order. unroll 2 keeps
        // two independent load->div chains in flight.
        float best = -2.0f;
        int   bp   = -1;
        #pragma unroll 2
        for (int p = st + c; p < en; p += CHUNKS) {
            float4 b  = s_box[p];
            float ix1 = fmaxf(rx1, b.x);
            float iy1 = fmaxf(ry1, b.y);
            float ix2 = fminf(rx2, b.z);
            float iy2 = fminf(ry2, b.w);
            float iw  = fmaxf(__fadd_rn(__fsub_rn(ix2, ix1), 1.0f), 0.0f);
            float ih  = fmaxf(__fadd_rn(__fsub_rn(iy2, iy1), 1.0f), 0.0f);
            float inter = __fmul_rn(iw, ih);
            // union = (area_r + area_g) - inter; contraction blocked (numpy)
            float uni = __fsub_rn(__fadd_rn(area_r, s_area[p]), inter);
            float v   = __fdiv_rn(inter, uni);
            if (v > best) { best = v; bp = p; }
        }

        // Cross-lane reduce over the 16-lane group; equal value -> smaller
        // position wins (== smaller original j within the batch).
        #pragma unroll
        for (int m = 1; m < CHUNKS; m <<= 1) {
            float vo = __shfl_xor(best, m, 64);
            int   po = __shfl_xor(bp,   m, 64);
            if (vo > best || (vo == best && po < bp)) { best = vo; bp = po; }
        }

        if (c == 0) {
            bool fg = (best >= 0.5f);      // bit-exact numpy max (or -2 -> false)
            int  pp = (bp < 0) ? 0 : bp;   // safe index; outputs zeroed if !fg

            float label = fg ? s_lab[pp] : 0.0f;   // integral 1..80, exact

            float4 g  = s_box[pp];
            float ew  = __fadd_rn(__fsub_rn(rx2, rx1), 1.0f);
            float eh  = __fadd_rn(__fsub_rn(ry2, ry1), 1.0f);
            float ecx = __fadd_rn(rx1, __fmul_rn(0.5f, ew));
            float ecy = __fadd_rn(ry1, __fmul_rn(0.5f, eh));
            float gw  = __fadd_rn(__fsub_rn(g.z, g.x), 1.0f);
            float gh  = __fadd_rn(__fsub_rn(g.w, g.y), 1.0f);
            float gcx = __fadd_rn(g.x, __fmul_rn(0.5f, gw));
            float gcy = __fadd_rn(g.y, __fmul_rn(0.5f, gh));

            float dx = __fdiv_rn(__fsub_rn(gcx, ecx), ew);
            float dy = __fdiv_rn(__fsub_rn(gcy, ecy), eh);
            float dw = logf(__fdiv_rn(gw, ew));
            float dh = logf(__fdiv_rn(gh, eh));

            if (!fg) { dx = 0.0f; dy = 0.0f; dw = 0.0f; dh = 0.0f; }
            float wgt = fg ? 1.0f : 0.0f;

            out[roi] = label;
            float4* dout = (float4*)(out + N_ROIS) + roi;
            *dout = make_float4(dx, dy, dw, dh);
            float4* wout = (float4*)(out + N_ROIS + 4 * N_ROIS) + roi;
            *wout = make_float4(wgt, wgt, wgt, wgt);
        }
    }
}

extern "C" void kernel_launch(void* const* d_in, const int* in_sizes, int n_in,
                              void* d_out, int out_size, void* d_ws, size_t ws_size,
                              hipStream_t stream) {
    const float* rois  = (const float*)d_in[0];   // (32768,5)
    const int*   roi_b = (const int*)d_in[1];     // (32768,)
    const float* gt    = (const float*)d_in[2];   // (1024,5)
    const int*   gt_b  = (const int*)d_in[3];     // (1024,)
    float*       out   = (float*)d_out;           // 32768*9 floats

    roi_target_kernel<<<MGRID, MBLOCK, 0, stream>>>(rois, roi_b, gt, gt_b, out);
}

// Round 9
// 66.080 us; speedup vs baseline: 1.1063x; 1.0195x over previous
//
#include <hip/hip_runtime.h>

#define N_ROIS 32768
#define N_GT   1024
#define N_IMG  8
#define CHUNKS 8                          // lanes cooperating per ROI
#define MBLOCK 512                        // 8 waves
#define MGRID  512                        // 2 blocks per CU resident
#define ROIS_PER_BLOCK (MBLOCK / CHUNKS)  // 64 (single pass)
#define GT_CHUNKS 16                      // 1024 / 64
#define CHUNKS_PER_WAVE 2                 // 16 chunks / 8 waves

// ---------------------------------------------------------------------------
// Single fused kernel (v7). R8 evidence: doubling grid (1->2 blocks/CU) gained
// only 2.7 us -> occupancy likely never doubled because no min-waves bound let
// the allocator exceed 128 VGPRs (2 waves/SIMD cap). v7: __launch_bounds__
// (512,4) forces VGPR<=128 (4 waves/SIMD = 2 blocks/CU); ROI data loaded
// after the sort instead of held in registers across it; CHUNKS 16->8 with a
// single pass (one epilogue, 3-step reduce, fewer live regs).
//
// Sort logic (ballot histograms -> wave-0 shfl scan -> stable scatter) is
// bit-identical to v3..v6: within each batch, sorted position order ==
// original-index order, reproducing numpy argmax first-index tie-break.
// ---------------------------------------------------------------------------
__global__ __launch_bounds__(MBLOCK, 4) void roi_target_kernel(
    const float* __restrict__ rois,       // (N_ROIS, 5)
    const int*   __restrict__ roi_b,      // (N_ROIS,)
    const float* __restrict__ gt_boxes,   // (N_GT, 5)
    const int*   __restrict__ gt_b,       // (N_GT,)
    float*       __restrict__ out)        // labels ++ deltas ++ bbwgts
{
    __shared__ float4 s_box[N_GT];        // 16 KB sorted (x1,y1,x2,y2)
    __shared__ float  s_area[N_GT];       //  4 KB sorted area
    __shared__ float  s_lab[N_GT];        //  4 KB sorted label
    __shared__ int    s_chist[GT_CHUNKS][N_IMG];
    __shared__ int    s_cbase[GT_CHUNKS][N_IMG];
    __shared__ int    s_seg[N_IMG + 1];

    int tid  = threadIdx.x;
    int lane = tid & 63;
    int wave = tid >> 6;                  // 0..7; owns chunks 2w, 2w+1

    unsigned long long lt_mask = (lane == 63) ? (~0ull >> 1)
                                              : ((1ull << lane) - 1ull);

    // ---- Sort phase 0: prefetch this wave's 2 GT chunks (one round-trip)
    int   bv[CHUNKS_PER_WAVE];
    float bx1[CHUNKS_PER_WAVE], by1[CHUNKS_PER_WAVE];
    float bx2[CHUNKS_PER_WAVE], by2[CHUNKS_PER_WAVE], blab[CHUNKS_PER_WAVE];
    #pragma unroll
    for (int k = 0; k < CHUNKS_PER_WAVE; ++k) {
        int j = (wave * CHUNKS_PER_WAVE + k) * 64 + lane;
        bv[k]   = gt_b[j];
        bx1[k]  = gt_boxes[j * 5 + 0];
        by1[k]  = gt_boxes[j * 5 + 1];
        bx2[k]  = gt_boxes[j * 5 + 2];
        by2[k]  = gt_boxes[j * 5 + 3];
        blab[k] = gt_boxes[j * 5 + 4];
    }

    // ---- Sort phase 1: per-chunk histograms + stable in-chunk ranks
    int rankc[CHUNKS_PER_WAVE];
    #pragma unroll
    for (int k = 0; k < CHUNKS_PER_WAVE; ++k) {
        int b = bv[k];
        unsigned long long mym = 0;
        #pragma unroll
        for (int bb = 0; bb < N_IMG; ++bb) {
            unsigned long long m = __ballot(b == bb);
            if (b == bb) mym = m;
            if (lane == bb) s_chist[wave * CHUNKS_PER_WAVE + k][bb] = __popcll(m);
        }
        rankc[k] = __popcll(mym & lt_mask);
    }
    __syncthreads();

    // ---- Sort phase 2: wave 0 computes chunk bases via in-register shfl scan
    if (wave == 0) {
        int myc    = lane & 15;           // chunk
        int myb_lo = lane >> 4;           // batches (2 slots per lane)
        int myb_hi = myb_lo + 4;
        int cnt_lo = s_chist[myc][myb_lo];
        int cnt_hi = s_chist[myc][myb_hi];
        int inc_lo = cnt_lo, inc_hi = cnt_hi;
        #pragma unroll
        for (int d = 1; d < 16; d <<= 1) {
            int t_lo = __shfl_up(inc_lo, d, 16);
            int t_hi = __shfl_up(inc_hi, d, 16);
            if (myc >= d) { inc_lo += t_lo; inc_hi += t_hi; }
        }
        int t0 = __shfl(inc_lo, 15, 64);
        int t1 = __shfl(inc_lo, 31, 64);
        int t2 = __shfl(inc_lo, 47, 64);
        int t3 = __shfl(inc_lo, 63, 64);
        int t4 = __shfl(inc_hi, 15, 64);
        int t5 = __shfl(inc_hi, 31, 64);
        int t6 = __shfl(inc_hi, 47, 64);
        int t7 = __shfl(inc_hi, 63, 64);

        int s0 = 0;
        int s1 = s0 + t0, s2 = s1 + t1, s3 = s2 + t2, s4 = s3 + t3;
        int s5 = s4 + t4, s6 = s5 + t5, s7 = s6 + t6, s8 = s7 + t7; // == N_GT

        if (lane == 0) {
            s_seg[0] = s0; s_seg[1] = s1; s_seg[2] = s2; s_seg[3] = s3;
            s_seg[4] = s4; s_seg[5] = s5; s_seg[6] = s6; s_seg[7] = s7;
            s_seg[8] = s8;
        }
        int seg_lo = (myb_lo == 0) ? s0 : (myb_lo == 1) ? s1
                   : (myb_lo == 2) ? s2 : s3;
        int seg_hi = (myb_hi == 4) ? s4 : (myb_hi == 5) ? s5
                   : (myb_hi == 6) ? s6 : s7;
        s_cbase[myc][myb_lo] = seg_lo + (inc_lo - cnt_lo);
        s_cbase[myc][myb_hi] = seg_hi + (inc_hi - cnt_hi);
    }
    __syncthreads();

    // ---- Sort phase 3: stable scatter into LDS from prefetched registers
    #pragma unroll
    for (int k = 0; k < CHUNKS_PER_WAVE; ++k) {
        int chunk = wave * CHUNKS_PER_WAVE + k;
        int rank  = s_cbase[chunk][bv[k]] + rankc[k];
        s_box[rank]  = make_float4(bx1[k], by1[k], bx2[k], by2[k]);
        // numpy f32 op order: ((x2-x1)+1) * ((y2-y1)+1)
        s_area[rank] = __fmul_rn(__fadd_rn(__fsub_rn(bx2[k], bx1[k]), 1.0f),
                                 __fadd_rn(__fsub_rn(by2[k], by1[k]), 1.0f));
        s_lab[rank]  = blab[k];
    }
    __syncthreads();

    // ---- ROI phase: 8 lanes per ROI scan the ROI's batch segment (~128 GT).
    // ROI data loaded here (L2-hot; latency hidden by 16 resident waves)
    // instead of held in registers across the sort phase.
    int c   = tid & (CHUNKS - 1);
    int roi = blockIdx.x * ROIS_PER_BLOCK + (tid >> 3);

    float rx1 = rois[roi * 5 + 0];
    float ry1 = rois[roi * 5 + 1];
    float rx2 = rois[roi * 5 + 2];
    float ry2 = rois[roi * 5 + 3];
    int   rb  = roi_b[roi];
    float area_r = __fmul_rn(__fadd_rn(__fsub_rn(rx2, rx1), 1.0f),
                             __fadd_rn(__fsub_rn(ry2, ry1), 1.0f));

    int st = s_seg[rb];
    int en = s_seg[rb + 1];

    // Positions increasing per lane, so strict > keeps the first max.
    // Within a batch, position order == original-j order. unroll 2 keeps
    // two independent load->div chains in flight.
    float best = -2.0f;
    int   bp   = -1;
    #pragma unroll 2
    for (int p = st + c; p < en; p += CHUNKS) {
        float4 b  = s_box[p];
        float ix1 = fmaxf(rx1, b.x);
        float iy1 = fmaxf(ry1, b.y);
        float ix2 = fminf(rx2, b.z);
        float iy2 = fminf(ry2, b.w);
        float iw  = fmaxf(__fadd_rn(__fsub_rn(ix2, ix1), 1.0f), 0.0f);
        float ih  = fmaxf(__fadd_rn(__fsub_rn(iy2, iy1), 1.0f), 0.0f);
        float inter = __fmul_rn(iw, ih);
        // union = (area_r + area_g) - inter; contraction blocked (numpy)
        float uni = __fsub_rn(__fadd_rn(area_r, s_area[p]), inter);
        float v   = __fdiv_rn(inter, uni);
        if (v > best) { best = v; bp = p; }
    }

    // Cross-lane reduce over the aligned 8-lane group; equal value -> smaller
    // position wins (== smaller original j within the batch).
    #pragma unroll
    for (int m = 1; m < CHUNKS; m <<= 1) {
        float vo = __shfl_xor(best, m, 64);
        int   po = __shfl_xor(bp,   m, 64);
        if (vo > best || (vo == best && po < bp)) { best = vo; bp = po; }
    }

    if (c == 0) {
        bool fg = (best >= 0.5f);          // bit-exact numpy max (or -2 -> false)
        int  pp = (bp < 0) ? 0 : bp;       // safe index; outputs zeroed if !fg

        float label = fg ? s_lab[pp] : 0.0f;   // integral 1..80, exact

        float4 g  = s_box[pp];
        float ew  = __fadd_rn(__fsub_rn(rx2, rx1), 1.0f);
        float eh  = __fadd_rn(__fsub_rn(ry2, ry1), 1.0f);
        float ecx = __fadd_rn(rx1, __fmul_rn(0.5f, ew));
        float ecy = __fadd_rn(ry1, __fmul_rn(0.5f, eh));
        float gw  = __fadd_rn(__fsub_rn(g.z, g.x), 1.0f);
        float gh  = __fadd_rn(__fsub_rn(g.w, g.y), 1.0f);
        float gcx = __fadd_rn(g.x, __fmul_rn(0.5f, gw));
        float gcy = __fadd_rn(g.y, __fmul_rn(0.5f, gh));

        float dx = __fdiv_rn(__fsub_rn(gcx, ecx), ew);
        float dy = __fdiv_rn(__fsub_rn(gcy, ecy), eh);
        float dw = logf(__fdiv_rn(gw, ew));
        float dh = logf(__fdiv_rn(gh, eh));

        if (!fg) { dx = 0.0f; dy = 0.0f; dw = 0.0f; dh = 0.0f; }
        float wgt = fg ? 1.0f : 0.0f;

        out[roi] = label;
        float4* dout = (float4*)(out + N_ROIS) + roi;
        *dout = make_float4(dx, dy, dw, dh);
        float4* wout = (float4*)(out + N_ROIS + 4 * N_ROIS) + roi;
        *wout = make_float4(wgt, wgt, wgt, wgt);
    }
}

extern "C" void kernel_launch(void* const* d_in, const int* in_sizes, int n_in,
                              void* d_out, int out_size, void* d_ws, size_t ws_size,
                              hipStream_t stream) {
    const float* rois  = (const float*)d_in[0];   // (32768,5)
    const int*   roi_b = (const int*)d_in[1];     // (32768,)
    const float* gt    = (const float*)d_in[2];   // (1024,5)
    const int*   gt_b  = (const int*)d_in[3];     // (1024,)
    float*       out   = (float*)d_out;           // 32768*9 floats

    roi_target_kernel<<<MGRID, MBLOCK, 0, stream>>>(rois, roi_b, gt, gt_b, out);
}